// Round 13
// baseline (339.276 us; speedup 1.0000x reference)
//
#include <hip/hip_runtime.h>
#include <hip/hip_fp16.h>
#include <hip/hip_cooperative_groups.h>
#include <math.h>

namespace cg = cooperative_groups;

// ---------------------------------------------------------------------------
// GAT 2-layer forward, N=50000, E=800000 (+N self loops), EMB=128,
// layer1: heads=8, C=16 (concat -> 128), layer2: heads=1, C=64.
// CSR-by-dst build per call, one gather pass per layer, softmax without
// max-subtraction. h1 fp16. MFMA GEMMs with augmented-weight alpha fusion.
// R20: atomic-free counting sort. R21: packed 4B pairs; gemm2 fused into
// agg1 epilogue. R23: 64-bucket (srcOct,dstOct) clustered CSR.
// R24 (agg unroll-8) REGRESSED: VGPR 60->76, occ 29->24.7%, FETCH 94->119MB
//   -> agg loops REVERTED to unroll-4 (R23 bodies). NCHUNK=4 kept.
// R25: COOPERATIVE SORT FUSION. subhist/scan1/scan23/scatter were 4 tiny
//   dispatches (~5-15us work each) paying launch+drain gaps. Fused into ONE
//   256-block cooperative kernel (1 block/CU -> residency guaranteed) with
//   grid.sync() between phases; 32KB LDS aliased (hist/scan-tmp/cursors).
//   Launches 8 -> 6.
// ---------------------------------------------------------------------------

typedef _Float16 f16x8 __attribute__((ext_vector_type(8)));
typedef float f32x4 __attribute__((ext_vector_type(4)));

#define NCHUNK 4      // chunk-blocks per bucket (64 x 4 = 256 blocks)
#define MAXBDIV 8192  // max nodes per dst octant (LDS array); N<=65536
#define CAP 16384     // per-bucket pair capacity (E/64=12.5k mean)

__device__ __forceinline__ float leaky_exp(float e) {
    e = (e > 0.f) ? e : 0.2f * e;
    return __expf(e);
}

__device__ __forceinline__ void acc16(float w, float4 hv0, float4 hv1,
                                      float* __restrict__ acc) {
    const __half2* p0 = (const __half2*)&hv0;
    const __half2* p1 = (const __half2*)&hv1;
#pragma unroll
    for (int k = 0; k < 4; k++) {
        float2 f = __half22float2(p0[k]);
        acc[2 * k] += w * f.x;
        acc[2 * k + 1] += w * f.y;
    }
#pragma unroll
    for (int k = 0; k < 4; k++) {
        float2 f = __half22float2(p1[k]);
        acc[8 + 2 * k] += w * f.x;
        acc[8 + 2 * k + 1] += w * f.y;
    }
}

__device__ __forceinline__ void acc8(float w, float4 hv,
                                     float* __restrict__ acc) {
    const __half2* hp = (const __half2*)&hv;
#pragma unroll
    for (int k = 0; k < 4; k++) {
        float2 f = __half22float2(hp[k]);
        acc[2 * k] += w * f.x;
        acc[2 * k + 1] += w * f.y;
    }
}

// ---------------------------------------------------------------------------
// K0: build transposed fp16 augmented weights (2 blocks, ~4us).
// ---------------------------------------------------------------------------
__global__ __launch_bounds__(256) void augw_kernel(const float* __restrict__ W1,
                                                   const float* __restrict__ a1s,
                                                   const float* __restrict__ a1d,
                                                   const float* __restrict__ W2,
                                                   const float* __restrict__ a2s,
                                                   const float* __restrict__ a2d,
                                                   _Float16* __restrict__ W1t,
                                                   _Float16* __restrict__ W2t) {
    int t = threadIdx.x;
    if (blockIdx.x == 0) {
        for (int i = t; i < 144 * 128; i += 256) {
            int c = i >> 7, k = i & 127;
            float v;
            if (c < 128) {
                v = W1[k * 128 + c];
            } else if (c < 136) {
                int h = c - 128; v = 0.f;
#pragma unroll
                for (int j = 0; j < 16; j++) v += W1[k * 128 + h * 16 + j] * a1s[h * 16 + j];
            } else {
                int h = c - 136; v = 0.f;
#pragma unroll
                for (int j = 0; j < 16; j++) v += W1[k * 128 + h * 16 + j] * a1d[h * 16 + j];
            }
            W1t[c * 128 + k] = (_Float16)v;
        }
    } else {
        for (int i = t; i < 80 * 128; i += 256) {
            int c = i >> 7, k = i & 127;
            float v = 0.f;
            if (c < 64) {
                v = W2[k * 64 + c];
            } else if (c == 64) {
                for (int j = 0; j < 64; j++) v += W2[k * 64 + j] * a2s[j];
            } else if (c == 65) {
                for (int j = 0; j < 64; j++) v += W2[k * 64 + j] * a2d[j];
            }
            W2t[c * 128 + k] = (_Float16)v;
        }
    }
}

// ---------------------------------------------------------------------------
// K1: fused gemm1 ∥ bucketing (64 buckets, packed 4B pairs).
// ---------------------------------------------------------------------------
__global__ __launch_bounds__(256) void gemm1_bucket_kernel(
        const float* __restrict__ x, const _Float16* __restrict__ W1t,
        __half* __restrict__ h1, float* __restrict__ als,
        float* __restrict__ ald, int N, int gridG1,
        const int* __restrict__ src, const int* __restrict__ dst, int E,
        int* __restrict__ bucketCnt, unsigned* __restrict__ pairs) {
    __shared__ _Float16 Xs[64 * 136];  // 17 KB (union with lcnt/lbase)
    int t = threadIdx.x;
    if ((int)blockIdx.x >= gridG1) {
        int* lcnt = (int*)Xs;
        int* lbase = lcnt + 64;
        if (t < 64) lcnt[t] = 0;
        __syncthreads();
        int bid = blockIdx.x - gridG1;
        int bdiv = (N + 7) >> 3;
        int i0 = (bid * 256 + t) * 4;
        int s_[4], d_[4], bk[4], rk[4];
        int nv = 0;
        if (i0 + 3 < E) {
            int4 d4 = *(const int4*)(dst + i0);
            int4 s4 = *(const int4*)(src + i0);
            s_[0] = s4.x; s_[1] = s4.y; s_[2] = s4.z; s_[3] = s4.w;
            d_[0] = d4.x; d_[1] = d4.y; d_[2] = d4.z; d_[3] = d4.w;
            nv = 4;
        } else {
            for (int k = i0; k < E && nv < 4; k++) {
                s_[nv] = src[k]; d_[nv] = dst[k]; nv++;
            }
        }
#pragma unroll 4
        for (int u = 0; u < 4; u++) {
            if (u < nv) {
                int b = (s_[u] / bdiv) * 8 + (d_[u] / bdiv);
                bk[u] = b;
                rk[u] = atomicAdd(&lcnt[b], 1);
            }
        }
        __syncthreads();
        if (t < 64) lbase[t] = atomicAdd(&bucketCnt[t * 16], lcnt[t]);
        __syncthreads();
#pragma unroll 4
        for (int k = 0; k < nv; k++) {
            unsigned dlocal = (unsigned)(d_[k] % bdiv);
            pairs[(size_t)bk[k] * CAP + lbase[bk[k]] + rk[k]] =
                (dlocal << 16) | (unsigned)s_[k];
        }
        return;
    }
    // ---- gemm1 path ----
    int row0 = blockIdx.x * 64;
    for (int i = t; i < 2048; i += 256) {
        int r = i >> 5, c4 = i & 31;
        int gr = row0 + r;
        float4 v = make_float4(0.f, 0.f, 0.f, 0.f);
        if (gr < N) v = *(const float4*)(x + (size_t)gr * 128 + c4 * 4);
        _Float16* dp = Xs + r * 136 + c4 * 4;
        dp[0] = (_Float16)v.x; dp[1] = (_Float16)v.y;
        dp[2] = (_Float16)v.z; dp[3] = (_Float16)v.w;
    }
    __syncthreads();
    int w = t >> 6, L = t & 63, m = L & 15, quad = L >> 4;
    f32x4 acc[9];
#pragma unroll
    for (int f = 0; f < 9; f++) acc[f] = (f32x4){0.f, 0.f, 0.f, 0.f};
    const _Float16* Arow = Xs + (w * 16 + m) * 136 + quad * 8;
    const _Float16* Brow = W1t + m * 128 + quad * 8;
#pragma unroll
    for (int kt = 0; kt < 4; kt++) {
        f16x8 a = *(const f16x8*)(Arow + kt * 32);
#pragma unroll
        for (int f = 0; f < 9; f++) {
            f16x8 b = *(const f16x8*)(Brow + f * 2048 + kt * 32);
            acc[f] = __builtin_amdgcn_mfma_f32_16x16x32_f16(a, b, acc[f], 0, 0, 0);
        }
    }
    int nbase = row0 + w * 16 + quad * 4;
#pragma unroll
    for (int r = 0; r < 4; r++) {
        int n = nbase + r;
        if (n < N) {
            __half* hrow = h1 + (size_t)n * 128 + m;
#pragma unroll
            for (int f = 0; f < 8; f++) hrow[f * 16] = __float2half(acc[f][r]);
            float v = acc[8][r];
            if (m < 8) als[n * 8 + m] = v;
            else ald[n * 8 + (m - 8)] = v;
        }
    }
}

// ---------------------------------------------------------------------------
// R25: COOPERATIVE SORT. One 256-block kernel, 4 phases with grid.sync():
//   P1 subhist (block bid: b=bid&63, j=bid>>6; LDS hist -> subcnt)
//   P2 scan1   (blocks [0,nbScan): deg sum + block-local prefix -> blocksum)
//   P3 scan23  (finalize rowstart; subcnt -> per-(srcOct,chunk,node) bases)
//   P4 scatter (LDS cursors from bases; esrc writes; zero global atomics)
// LDS: one 32KB int buffer aliased across phases.
// ---------------------------------------------------------------------------
__global__ __launch_bounds__(256) void sort_kernel(
        const int* __restrict__ bucketCnt, const unsigned* __restrict__ pairs,
        int N, int E, int* __restrict__ subcnt, int* __restrict__ rowstart,
        int* __restrict__ blocksum, int* __restrict__ esrc) {
    cg::grid_group grid = cg::this_grid();
    __shared__ int lds[MAXBDIV];  // 32 KB, aliased per phase
    int t = threadIdx.x;
    int bdiv = (N + 7) >> 3;
    int b = blockIdx.x & 63;
    int j = blockIdx.x >> 6;
    int cnt = bucketCnt[b * 16];
    int chunk = (cnt + NCHUNK - 1) / NCHUNK;
    int lo = j * chunk;
    int hi = min(lo + chunk, cnt);
    const unsigned* plist = pairs + (size_t)b * CAP;

    // ---- P1: subhist ----
    for (int i = t; i < bdiv; i += 256) lds[i] = 0;
    __syncthreads();
    for (int i = lo + t; i < hi; i += 256) {
        atomicAdd(&lds[plist[i] >> 16], 1);
    }
    __syncthreads();
    {
        int* out = subcnt + (size_t)(b * NCHUNK + j) * bdiv;
        for (int i = t; i < bdiv; i += 256) out[i] = lds[i];
    }
    grid.sync();

    // ---- P2: scan1 ----
    int nbScan = (N + 255) / 256;
    if ((int)blockIdx.x < nbScan) {
        int i = blockIdx.x * 256 + t;
        int v = 0;
        if (i < N) {
            int dd = i / bdiv;
            int local = i - dd * bdiv;
#pragma unroll
            for (int so = 0; so < 8; so++) {
                const int* sc = subcnt + ((size_t)(so * 8 + dd) * NCHUNK) * bdiv + local;
#pragma unroll
                for (int jj = 0; jj < NCHUNK; jj++) v += sc[(size_t)jj * bdiv];
            }
        }
        lds[t] = v;
        __syncthreads();
        for (int off = 1; off < 256; off <<= 1) {
            int xv = (t >= off) ? lds[t - off] : 0;
            __syncthreads();
            lds[t] += xv;
            __syncthreads();
        }
        if (i < N) rowstart[i] = lds[t] - v;
        if (t == 255) blocksum[blockIdx.x] = lds[t];
    }
    grid.sync();

    // ---- P3: scan23 ----
    int nb23 = (N + 256) / 256;
    if ((int)blockIdx.x < nb23) {
        lds[t] = (t < nbScan && t < (int)blockIdx.x) ? blocksum[t] : 0;
        __syncthreads();
#pragma unroll
        for (int off = 128; off > 0; off >>= 1) {
            if (t < off) lds[t] += lds[t + off];
            __syncthreads();
        }
        int offset = lds[0];
        int i = blockIdx.x * 256 + t;
        if (i < N) {
            int v = rowstart[i] + offset;
            rowstart[i] = v;
            int dd = i / bdiv;
            int local = i - dd * bdiv;
            int c = v;
#pragma unroll
            for (int so = 0; so < 8; so++) {
                int* sc = subcnt + ((size_t)(so * 8 + dd) * NCHUNK) * bdiv + local;
#pragma unroll
                for (int jj = 0; jj < NCHUNK; jj++) {
                    int cj = sc[(size_t)jj * bdiv];
                    sc[(size_t)jj * bdiv] = c;
                    c += cj;
                }
            }
        } else if (i == N) {
            rowstart[N] = E;
        }
    }
    grid.sync();

    // ---- P4: scatter ----
    {
        const int* base = subcnt + (size_t)(b * NCHUNK + j) * bdiv;
        for (int i = t; i < bdiv; i += 256) lds[i] = base[i];
        __syncthreads();
        for (int i = lo + t; i < hi; i += 256) {
            unsigned p = plist[i];
            int pos = atomicAdd(&lds[p >> 16], 1);
            esrc[pos] = (int)(p & 0xFFFFu);
        }
    }
}

// ---------------------------------------------------------------------------
// agg1 + fused gemm2 (R23 body: unroll-4 batched loads).
// ---------------------------------------------------------------------------
__global__ __launch_bounds__(256) void agg1_gemm2_kernel(
        const __half* __restrict__ h1, const float* __restrict__ als,
        const float* __restrict__ ald, const int* __restrict__ rowstart,
        const int* __restrict__ esrc, const float* __restrict__ b1,
        const _Float16* __restrict__ W2t, __half* __restrict__ h2,
        float* __restrict__ al2s, float* __restrict__ al2d, int N) {
    __shared__ _Float16 actS[32 * 136];  // 8.7 KB
    int t = threadIdx.x;
    int lane = t & 63;
    int grp = lane >> 3;
    int q = lane & 7;
    int bdiv = (N + 7) >> 3;
    int lrow = (t >> 6) * 8 + grp;
    int ln = (blockIdx.x >> 3) * 32 + lrow;
    int n = (blockIdx.x & 7) * bdiv + ln;
    bool valid = (ln < bdiv) && (n < N);
    const float4* h1v = (const float4*)h1;
    float acc[16];
#pragma unroll
    for (int k = 0; k < 16; k++) acc[k] = 0.f;
    float wsum = 0.f;
    int beg = 0, end = 0;
    float adv = 0.f;
    if (valid) {
        adv = ald[n * 8 + q];
        float wself = leaky_exp(als[n * 8 + q] + adv);
        wsum = wself;
        acc16(wself, h1v[(size_t)n * 16 + 2 * q], h1v[(size_t)n * 16 + 2 * q + 1], acc);
        beg = rowstart[n];
        end = rowstart[n + 1];
    }
    int j = beg;
    for (; j + 4 <= end; j += 4) {
        int s0 = esrc[j], s1 = esrc[j + 1], s2 = esrc[j + 2], s3 = esrc[j + 3];
        float4 a0 = h1v[(size_t)s0 * 16 + 2 * q], b0 = h1v[(size_t)s0 * 16 + 2 * q + 1];
        float4 a1 = h1v[(size_t)s1 * 16 + 2 * q], b1v = h1v[(size_t)s1 * 16 + 2 * q + 1];
        float4 a2 = h1v[(size_t)s2 * 16 + 2 * q], b2 = h1v[(size_t)s2 * 16 + 2 * q + 1];
        float4 a3 = h1v[(size_t)s3 * 16 + 2 * q], b3 = h1v[(size_t)s3 * 16 + 2 * q + 1];
        float e0 = als[s0 * 8 + q], e1 = als[s1 * 8 + q];
        float e2 = als[s2 * 8 + q], e3 = als[s3 * 8 + q];
        float w0 = leaky_exp(e0 + adv), w1 = leaky_exp(e1 + adv);
        float w2 = leaky_exp(e2 + adv), w3 = leaky_exp(e3 + adv);
        wsum += (w0 + w1) + (w2 + w3);
        acc16(w0, a0, b0, acc);
        acc16(w1, a1, b1v, acc);
        acc16(w2, a2, b2, acc);
        acc16(w3, a3, b3, acc);
    }
    for (; j < end; j++) {
        int s = esrc[j];
        float w = leaky_exp(als[s * 8 + q] + adv);
        wsum += w;
        acc16(w, h1v[(size_t)s * 16 + 2 * q], h1v[(size_t)s * 16 + 2 * q + 1], acc);
    }
    __align__(16) __half2 po[8];
    if (valid) {
        float inv = 1.f / (wsum + 1e-16f);
        const float* bf = b1 + q * 16;
#pragma unroll
        for (int k = 0; k < 8; k++) {
            float o0 = acc[2 * k] * inv + bf[2 * k];
            float o1 = acc[2 * k + 1] * inv + bf[2 * k + 1];
            o0 = (o0 > 0.f) ? o0 : (__expf(o0) - 1.f);  // ELU
            o1 = (o1 > 0.f) ? o1 : (__expf(o1) - 1.f);
            po[k] = __floats2half2_rn(o0, o1);
        }
    } else {
#pragma unroll
        for (int k = 0; k < 8; k++) po[k] = __floats2half2_rn(0.f, 0.f);
    }
    *(float4*)(actS + lrow * 136 + q * 16) = ((float4*)po)[0];
    *(float4*)(actS + lrow * 136 + q * 16 + 8) = ((float4*)po)[1];
    __syncthreads();
    int w4w = t >> 6;
    int m = lane & 15, quad = lane >> 4;
    int rt = w4w & 1;
    int ctbase = (w4w < 2) ? 0 : 1;
    f32x4 acc2[3];
#pragma unroll
    for (int f = 0; f < 3; f++) acc2[f] = (f32x4){0.f, 0.f, 0.f, 0.f};
    const _Float16* Arow2 = actS + (rt * 16 + m) * 136 + quad * 8;
    const _Float16* Brow2 = W2t + m * 128 + quad * 8;
#pragma unroll
    for (int kt = 0; kt < 4; kt++) {
        f16x8 a = *(const f16x8*)(Arow2 + kt * 32);
#pragma unroll
        for (int f = 0; f < 3; f++) {
            int ctf = ctbase + 2 * f;
            if (ctf < 5) {
                f16x8 bb = *(const f16x8*)(Brow2 + ctf * 2048 + kt * 32);
                acc2[f] = __builtin_amdgcn_mfma_f32_16x16x32_f16(a, bb, acc2[f], 0, 0, 0);
            }
        }
    }
    int secbase = (blockIdx.x & 7) * bdiv;
    int lnbase = (blockIdx.x >> 3) * 32 + rt * 16 + quad * 4;
#pragma unroll
    for (int r = 0; r < 4; r++) {
        int ln2 = lnbase + r;
        int n2 = secbase + ln2;
        if (ln2 < bdiv && n2 < N) {
#pragma unroll
            for (int f = 0; f < 3; f++) {
                int ctf = ctbase + 2 * f;
                if (ctf < 4) {
                    h2[(size_t)n2 * 64 + ctf * 16 + m] = __float2half(acc2[f][r]);
                } else if (ctf == 4) {
                    if (m == 0) al2s[n2] = acc2[f][r];
                    else if (m == 1) al2d[n2] = acc2[f][r];
                }
            }
        }
    }
}

// Aggregation layer 2 (R23 body: unroll-4).
__global__ __launch_bounds__(256) void agg2_kernel(const __half* __restrict__ h2,
                                                   const float* __restrict__ al2s,
                                                   const float* __restrict__ al2d,
                                                   const int* __restrict__ rowstart,
                                                   const int* __restrict__ esrc,
                                                   const float* __restrict__ b2,
                                                   float* __restrict__ out, int N) {
    int t = threadIdx.x;
    int lane = t & 63;
    int grp = lane >> 3;
    int q = lane & 7;
    int bdiv = (N + 7) >> 3;
    int ln = (blockIdx.x >> 3) * 32 + (t >> 6) * 8 + grp;
    if (ln >= bdiv) return;
    int n = (blockIdx.x & 7) * bdiv + ln;
    if (n >= N) return;
    const float4* h2v = (const float4*)h2;
    float adv = al2d[n];
    float acc[8];
#pragma unroll
    for (int k = 0; k < 8; k++) acc[k] = 0.f;
    float wsum = 0.f;
    {  // self loop
        float w = leaky_exp(al2s[n] + adv);
        wsum += w;
        acc8(w, h2v[(size_t)n * 8 + q], acc);
    }
    int beg = rowstart[n], end = rowstart[n + 1];
    int j = beg;
    for (; j + 4 <= end; j += 4) {
        int s0 = esrc[j], s1 = esrc[j + 1], s2 = esrc[j + 2], s3 = esrc[j + 3];
        float4 a0 = h2v[(size_t)s0 * 8 + q];
        float4 a1 = h2v[(size_t)s1 * 8 + q];
        float4 a2 = h2v[(size_t)s2 * 8 + q];
        float4 a3 = h2v[(size_t)s3 * 8 + q];
        float e0 = al2s[s0], e1 = al2s[s1], e2 = al2s[s2], e3 = al2s[s3];
        float w0 = leaky_exp(e0 + adv), w1 = leaky_exp(e1 + adv);
        float w2 = leaky_exp(e2 + adv), w3 = leaky_exp(e3 + adv);
        wsum += (w0 + w1) + (w2 + w3);
        acc8(w0, a0, acc);
        acc8(w1, a1, acc);
        acc8(w2, a2, acc);
        acc8(w3, a3, acc);
    }
    for (; j < end; j++) {
        int s = esrc[j];
        float w = leaky_exp(al2s[s] + adv);
        wsum += w;
        acc8(w, h2v[(size_t)s * 8 + q], acc);
    }
    float inv = 1.f / (wsum + 1e-16f);
    const float* bf = b2 + q * 8;
    float4* ov = (float4*)(out + (size_t)n * 64 + q * 8);
    ov[0] = make_float4(acc[0] * inv + bf[0], acc[1] * inv + bf[1],
                        acc[2] * inv + bf[2], acc[3] * inv + bf[3]);
    ov[1] = make_float4(acc[4] * inv + bf[4], acc[5] * inv + bf[5],
                        acc[6] * inv + bf[6], acc[7] * inv + bf[7]);
}

extern "C" void kernel_launch(void* const* d_in, const int* in_sizes, int n_in,
                              void* d_out, int out_size, void* d_ws, size_t ws_size,
                              hipStream_t stream) {
    (void)n_in; (void)out_size; (void)ws_size;
    const float* x   = (const float*)d_in[0];
    const int*   ei  = (const int*)d_in[1];
    const float* W1  = (const float*)d_in[2];
    const float* a1s = (const float*)d_in[3];
    const float* a1d = (const float*)d_in[4];
    const float* b1  = (const float*)d_in[5];
    const float* W2  = (const float*)d_in[6];
    const float* a2s = (const float*)d_in[7];
    const float* a2d = (const float*)d_in[8];
    const float* b2  = (const float*)d_in[9];
    float* out = (float*)d_out;

    const int N = in_sizes[0] / 128;
    const int E = in_sizes[1] / 2;
    const int* src = ei;
    const int* dst = ei + E;
    const int bdiv = (N + 7) / 8;

    char* wp = (char*)d_ws;
    auto alloc = [&](size_t bytes) -> void* {
        void* p = (void*)wp;
        wp += (bytes + 255) & ~(size_t)255;
        return p;
    };
    __half* h1   = (__half*)alloc((size_t)N * 128 * 2);
    __half* h2   = (__half*)alloc((size_t)N * 64 * 2 + 64 * 256);  // +pad
    float* al1s = (float*)alloc((size_t)N * 8 * 4);
    float* al1d = (float*)alloc((size_t)N * 8 * 4);
    float* al2s = (float*)alloc((size_t)N * 4);
    float* al2d = (float*)alloc((size_t)N * 4);
    int* bucketCnt = (int*)alloc(64 * 16 * 4);
    int* subcnt   = (int*)alloc((size_t)64 * NCHUNK * bdiv * 4);  // 6.4MB
    int* rowstart = (int*)alloc((size_t)(N + 1) * 4);
    int* esrc     = (int*)alloc((size_t)E * 4);
    unsigned* pairs = (unsigned*)alloc((size_t)64 * CAP * 4);  // 4MB
    int* blocksum = (int*)alloc(256 * 4);
    _Float16* W1t = (_Float16*)alloc(144 * 128 * 2);
    _Float16* W2t = (_Float16*)alloc(80 * 128 * 2);

    const int gridH  = (E + 1023) / 1024;
    const int gridG1 = (N + 63) / 64;
    const int gridAggN = 8 * ((bdiv + 31) / 32);

    hipMemsetAsync(bucketCnt, 0, 64 * 16 * 4, stream);

    // K0: augmented weights (tiny, serial)
    augw_kernel<<<2, 256, 0, stream>>>(W1, a1s, a1d, W2, a2s, a2d, W1t, W2t);
    // K1: gemm1 ∥ 64-bucket compaction
    gemm1_bucket_kernel<<<gridG1 + gridH, 256, 0, stream>>>(
        x, W1t, h1, al1s, al1d, N, gridG1, src, dst, E, bucketCnt, pairs);
    // K2: cooperative sort (subhist + scans + scatter, 3 grid syncs)
    {
        int Nv = N, Ev = E;
        void* args[] = {(void*)&bucketCnt, (void*)&pairs, (void*)&Nv, (void*)&Ev,
                        (void*)&subcnt, (void*)&rowstart, (void*)&blocksum,
                        (void*)&esrc};
        hipLaunchCooperativeKernel((void*)sort_kernel, dim3(64 * NCHUNK),
                                   dim3(256), args, 0, stream);
    }
    // agg1 with fused gemm2 epilogue
    agg1_gemm2_kernel<<<gridAggN, 256, 0, stream>>>(h1, al1s, al1d, rowstart, esrc,
                                                    b1, W2t, h2, al2s, al2d, N);
    agg2_kernel<<<gridAggN, 256, 0, stream>>>(h2, al2s, al2d, rowstart, esrc, b2, out, N);
}

// Round 14
// 215.852 us; speedup vs baseline: 1.5718x; 1.5718x over previous
//
#include <hip/hip_runtime.h>
#include <hip/hip_fp16.h>
#include <math.h>

// ---------------------------------------------------------------------------
// GAT 2-layer forward, N=50000, E=800000 (+N self loops), EMB=128,
// layer1: heads=8, C=16 (concat -> 128), layer2: heads=1, C=64.
// CSR-by-dst build per call, one gather pass per layer, softmax without
// max-subtraction. h1 fp16. MFMA GEMMs with augmented-weight alpha fusion.
// R20: atomic-free counting sort (8 dst buckets). R21: packed 4B pairs;
// gemm2 fused into agg1 epilogue.  [BEST: 220.8us]
// R22 (pipeline split) REGRESSED. R23 (64-bucket src clustering) ~neutral.
// R24 (agg unroll-8) REGRESSED (VGPR/occupancy). R25 (cooperative sort)
// REGRESSED BADLY (grid.sync ~30us each on 8 XCDs).
// R26: R21 revert + (a) esrc SOFTWARE PREFETCH in agg loops: next group's
//   4 indices load while current gathers are in flight -> removes the
//   esrc L2 hop (~200cyc) from the steady-state dependent chain;
//   (b) bucketCnt zeroing folded into augw block 0 (one fewer dispatch).
// ---------------------------------------------------------------------------

typedef _Float16 f16x8 __attribute__((ext_vector_type(8)));
typedef float f32x4 __attribute__((ext_vector_type(4)));

#define NCHUNK 32    // chunk-blocks per bucket
#define MAXBDIV 8192 // max nodes per bucket (LDS hist ints); N<=65536

__device__ __forceinline__ float leaky_exp(float e) {
    e = (e > 0.f) ? e : 0.2f * e;
    return __expf(e);
}

__device__ __forceinline__ void acc16(float w, float4 hv0, float4 hv1,
                                      float* __restrict__ acc) {
    const __half2* p0 = (const __half2*)&hv0;
    const __half2* p1 = (const __half2*)&hv1;
#pragma unroll
    for (int k = 0; k < 4; k++) {
        float2 f = __half22float2(p0[k]);
        acc[2 * k] += w * f.x;
        acc[2 * k + 1] += w * f.y;
    }
#pragma unroll
    for (int k = 0; k < 4; k++) {
        float2 f = __half22float2(p1[k]);
        acc[8 + 2 * k] += w * f.x;
        acc[8 + 2 * k + 1] += w * f.y;
    }
}

__device__ __forceinline__ void acc8(float w, float4 hv,
                                     float* __restrict__ acc) {
    const __half2* hp = (const __half2*)&hv;
#pragma unroll
    for (int k = 0; k < 4; k++) {
        float2 f = __half22float2(hp[k]);
        acc[2 * k] += w * f.x;
        acc[2 * k + 1] += w * f.y;
    }
}

// ---------------------------------------------------------------------------
// K0: build transposed fp16 augmented weights; block 0 also zeroes bucketCnt.
// ---------------------------------------------------------------------------
__global__ __launch_bounds__(256) void augw_kernel(const float* __restrict__ W1,
                                                   const float* __restrict__ a1s,
                                                   const float* __restrict__ a1d,
                                                   const float* __restrict__ W2,
                                                   const float* __restrict__ a2s,
                                                   const float* __restrict__ a2d,
                                                   _Float16* __restrict__ W1t,
                                                   _Float16* __restrict__ W2t,
                                                   int* __restrict__ bucketCnt) {
    int t = threadIdx.x;
    if (blockIdx.x == 0) {
        if (t < 128) bucketCnt[t] = 0;  // 8*16 ints
        for (int i = t; i < 144 * 128; i += 256) {
            int c = i >> 7, k = i & 127;
            float v;
            if (c < 128) {
                v = W1[k * 128 + c];
            } else if (c < 136) {
                int h = c - 128; v = 0.f;
#pragma unroll
                for (int j = 0; j < 16; j++) v += W1[k * 128 + h * 16 + j] * a1s[h * 16 + j];
            } else {
                int h = c - 136; v = 0.f;
#pragma unroll
                for (int j = 0; j < 16; j++) v += W1[k * 128 + h * 16 + j] * a1d[h * 16 + j];
            }
            W1t[c * 128 + k] = (_Float16)v;
        }
    } else {
        for (int i = t; i < 80 * 128; i += 256) {
            int c = i >> 7, k = i & 127;
            float v = 0.f;
            if (c < 64) {
                v = W2[k * 64 + c];
            } else if (c == 64) {
                for (int j = 0; j < 64; j++) v += W2[k * 64 + j] * a2s[j];
            } else if (c == 65) {
                for (int j = 0; j < 64; j++) v += W2[k * 64 + j] * a2d[j];
            }
            W2t[c * 128 + k] = (_Float16)v;
        }
    }
}

// ---------------------------------------------------------------------------
// K1: fused gemm1 ∥ bucketing. Blocks [0,gridG1) = MFMA GEMM1; blocks >=
// gridG1 = ballot-ranked bucket compaction of packed (dlocal<<16|src).
// ---------------------------------------------------------------------------
__global__ __launch_bounds__(256) void gemm1_bucket_kernel(
        const float* __restrict__ x, const _Float16* __restrict__ W1t,
        __half* __restrict__ h1, float* __restrict__ als,
        float* __restrict__ ald, int N, int gridG1,
        const int* __restrict__ src, const int* __restrict__ dst, int E,
        int* __restrict__ bucketCnt, unsigned* __restrict__ pairs) {
    __shared__ _Float16 Xs[64 * 136];  // 17 KB (union with bucketing lcnt/lbase)
    int t = threadIdx.x;
    if ((int)blockIdx.x >= gridG1) {
        // ---- bucketing ----
        int* lcnt = (int*)Xs;
        int* lbase = lcnt + 8;
        if (t < 8) lcnt[t] = 0;
        __syncthreads();
        int bid = blockIdx.x - gridG1;
        int bdiv = (N + 7) >> 3;
        int i0 = (bid * 256 + t) * 4;
        int s_[4], d_[4], bk[4], rk[4];
        int nv = 0;
        if (i0 + 3 < E) {
            int4 d4 = *(const int4*)(dst + i0);
            int4 s4 = *(const int4*)(src + i0);
            s_[0] = s4.x; s_[1] = s4.y; s_[2] = s4.z; s_[3] = s4.w;
            d_[0] = d4.x; d_[1] = d4.y; d_[2] = d4.z; d_[3] = d4.w;
            nv = 4;
        } else {
            for (int k = i0; k < E && nv < 4; k++) {
                s_[nv] = src[k]; d_[nv] = dst[k]; nv++;
            }
        }
        int lane = t & 63;
        unsigned long long below = (lane == 0) ? 0ULL : (~0ULL >> (64 - lane));
#pragma unroll
        for (int u = 0; u < 4; u++) {
            bool v = (u < nv);
            int d = v ? d_[u] : 0;
            int b = d / bdiv;
            unsigned long long m0 = __ballot(b & 1);
            unsigned long long m1 = __ballot(b & 2);
            unsigned long long m2 = __ballot(b & 4);
            unsigned long long vm = __ballot(v);
            unsigned long long me = ((b & 1) ? m0 : ~m0) & ((b & 2) ? m1 : ~m1) &
                                    ((b & 4) ? m2 : ~m2) & vm;
            int leader = __ffsll((unsigned long long)me) - 1;
            int ldr = (leader < 0) ? 0 : leader;  // valid index even if me==0
            int cnt = __popcll(me);
            int rank = __popcll(me & below);
            int base = 0;
            if (v && lane == leader) base = atomicAdd(&lcnt[b], cnt);
            base = __shfl(base, ldr);
            bk[u] = b;
            rk[u] = base + rank;
        }
        __syncthreads();
        if (t < 8) lbase[t] = atomicAdd(&bucketCnt[t * 16], lcnt[t]);
        __syncthreads();
#pragma unroll 4
        for (int k = 0; k < nv; k++) {
            unsigned dlocal = (unsigned)(d_[k] - bk[k] * ((N + 7) >> 3));
            pairs[(size_t)bk[k] * E + lbase[bk[k]] + rk[k]] =
                (dlocal << 16) | (unsigned)s_[k];
        }
        return;
    }
    // ---- gemm1 path ----
    int row0 = blockIdx.x * 64;
    for (int i = t; i < 2048; i += 256) {
        int r = i >> 5, c4 = i & 31;
        int gr = row0 + r;
        float4 v = make_float4(0.f, 0.f, 0.f, 0.f);
        if (gr < N) v = *(const float4*)(x + (size_t)gr * 128 + c4 * 4);
        _Float16* dp = Xs + r * 136 + c4 * 4;
        dp[0] = (_Float16)v.x; dp[1] = (_Float16)v.y;
        dp[2] = (_Float16)v.z; dp[3] = (_Float16)v.w;
    }
    __syncthreads();
    int w = t >> 6, L = t & 63, m = L & 15, quad = L >> 4;
    f32x4 acc[9];
#pragma unroll
    for (int f = 0; f < 9; f++) acc[f] = (f32x4){0.f, 0.f, 0.f, 0.f};
    const _Float16* Arow = Xs + (w * 16 + m) * 136 + quad * 8;
    const _Float16* Brow = W1t + m * 128 + quad * 8;
#pragma unroll
    for (int kt = 0; kt < 4; kt++) {
        f16x8 a = *(const f16x8*)(Arow + kt * 32);
#pragma unroll
        for (int f = 0; f < 9; f++) {
            f16x8 b = *(const f16x8*)(Brow + f * 2048 + kt * 32);
            acc[f] = __builtin_amdgcn_mfma_f32_16x16x32_f16(a, b, acc[f], 0, 0, 0);
        }
    }
    int nbase = row0 + w * 16 + quad * 4;
#pragma unroll
    for (int r = 0; r < 4; r++) {
        int n = nbase + r;
        if (n < N) {
            __half* hrow = h1 + (size_t)n * 128 + m;
#pragma unroll
            for (int f = 0; f < 8; f++) hrow[f * 16] = __float2half(acc[f][r]);
            float v = acc[8][r];
            if (m < 8) als[n * 8 + m] = v;
            else ald[n * 8 + (m - 8)] = v;
        }
    }
}

// ---------------------------------------------------------------------------
// K1b: per-chunk LDS histograms over packed pairs (dlocal = p>>16).
// ---------------------------------------------------------------------------
__global__ __launch_bounds__(256) void subhist_kernel(
        const int* __restrict__ bucketCnt, const unsigned* __restrict__ pairs,
        int E, int N, int* __restrict__ subcnt) {
    __shared__ int hist[MAXBDIV];  // 32 KB
    int t = threadIdx.x;
    int b = blockIdx.x & 7;
    int j = blockIdx.x >> 3;
    int bdiv = (N + 7) >> 3;
    for (int i = t; i < bdiv; i += 256) hist[i] = 0;
    __syncthreads();
    int cnt = bucketCnt[b * 16];
    int chunk = (cnt + NCHUNK - 1) / NCHUNK;
    int lo = j * chunk;
    int hi = min(lo + chunk, cnt);
    const unsigned* plist = pairs + (size_t)b * E;
    for (int i = lo + t; i < hi; i += 256) {
        atomicAdd(&hist[plist[i] >> 16], 1);
    }
    __syncthreads();
    int* out = subcnt + (size_t)(b * NCHUNK + j) * bdiv;
    for (int i = t; i < bdiv; i += 256) out[i] = hist[i];
}

// scan1: deg[n] = sum_j subcnt; block-local scan.
__global__ __launch_bounds__(256) void scan1_kernel(const int* __restrict__ subcnt,
                                                    int N,
                                                    int* __restrict__ rowstart,
                                                    int* __restrict__ blocksum) {
    __shared__ int tmp[256];
    int t = threadIdx.x;
    int i = blockIdx.x * 256 + t;
    int bdiv = (N + 7) >> 3;
    int v = 0;
    if (i < N) {
        int b = i / bdiv;
        int local = i - b * bdiv;
        const int* sc = subcnt + (size_t)b * NCHUNK * bdiv + local;
#pragma unroll
        for (int j = 0; j < NCHUNK; j++) v += sc[(size_t)j * bdiv];
    }
    tmp[t] = v;
    __syncthreads();
    for (int off = 1; off < 256; off <<= 1) {
        int x = (t >= off) ? tmp[t - off] : 0;
        __syncthreads();
        tmp[t] += x;
        __syncthreads();
    }
    if (i < N) rowstart[i] = tmp[t] - v;
    if (t == 255) blocksum[blockIdx.x] = tmp[t];
}

// scan23: finalize rowstart; convert subcnt in-place into scatter BASES.
__global__ __launch_bounds__(256) void scan23_kernel(int* __restrict__ rowstart,
                                                     const int* __restrict__ blocksum,
                                                     int nb,
                                                     int* __restrict__ subcnt,
                                                     int N, int E) {
    __shared__ int sdata[256];
    int t = threadIdx.x;
    int bx = blockIdx.x;
    sdata[t] = (t < nb && t < bx) ? blocksum[t] : 0;
    __syncthreads();
#pragma unroll
    for (int off = 128; off > 0; off >>= 1) {
        if (t < off) sdata[t] += sdata[t + off];
        __syncthreads();
    }
    int offset = sdata[0];
    int i = bx * 256 + t;
    int bdiv = (N + 7) >> 3;
    if (i < N) {
        int v = rowstart[i] + offset;
        rowstart[i] = v;
        int b = i / bdiv;
        int local = i - b * bdiv;
        int* sc = subcnt + (size_t)b * NCHUNK * bdiv + local;
        int c = v;
#pragma unroll
        for (int j = 0; j < NCHUNK; j++) {
            int cj = sc[(size_t)j * bdiv];
            sc[(size_t)j * bdiv] = c;
            c += cj;
        }
    } else if (i == N) {
        rowstart[N] = E;
    }
}

// ---------------------------------------------------------------------------
// K4: scatter via LDS cursors; packed pairs. Zero global atomics.
// ---------------------------------------------------------------------------
__global__ __launch_bounds__(256) void scatter_kernel(
        const int* __restrict__ bucketCnt, const unsigned* __restrict__ pairs,
        int E, int N, const int* __restrict__ subcnt, int* __restrict__ esrc) {
    __shared__ int lcur[MAXBDIV];  // 32 KB
    int t = threadIdx.x;
    int b = blockIdx.x & 7;
    int j = blockIdx.x >> 3;
    int bdiv = (N + 7) >> 3;
    const int* base = subcnt + (size_t)(b * NCHUNK + j) * bdiv;
    for (int i = t; i < bdiv; i += 256) lcur[i] = base[i];
    __syncthreads();
    int cnt = bucketCnt[b * 16];
    int chunk = (cnt + NCHUNK - 1) / NCHUNK;
    int lo = j * chunk;
    int hi = min(lo + chunk, cnt);
    const unsigned* plist = pairs + (size_t)b * E;
    for (int i = lo + t; i < hi; i += 256) {
        unsigned p = plist[i];
        int pos = atomicAdd(&lcur[p >> 16], 1);
        esrc[pos] = (int)(p & 0xFFFFu);
    }
}

// ---------------------------------------------------------------------------
// agg1 + fused gemm2. R26: esrc software prefetch (next 4 indices load
// while current 12 gathers are in flight).
// ---------------------------------------------------------------------------
__global__ __launch_bounds__(256) void agg1_gemm2_kernel(
        const __half* __restrict__ h1, const float* __restrict__ als,
        const float* __restrict__ ald, const int* __restrict__ rowstart,
        const int* __restrict__ esrc, const float* __restrict__ b1,
        const _Float16* __restrict__ W2t, __half* __restrict__ h2,
        float* __restrict__ al2s, float* __restrict__ al2d, int N) {
    __shared__ _Float16 actS[32 * 136];  // 8.7 KB
    int t = threadIdx.x;
    int lane = t & 63;
    int grp = lane >> 3;
    int q = lane & 7;
    int bdiv = (N + 7) >> 3;
    int lrow = (t >> 6) * 8 + grp;
    int ln = (blockIdx.x >> 3) * 32 + lrow;
    int n = (blockIdx.x & 7) * bdiv + ln;
    bool valid = (ln < bdiv) && (n < N);
    const float4* h1v = (const float4*)h1;
    float acc[16];
#pragma unroll
    for (int k = 0; k < 16; k++) acc[k] = 0.f;
    float wsum = 0.f;
    int beg = 0, end = 0;
    float adv = 0.f;
    if (valid) {
        adv = ald[n * 8 + q];
        float wself = leaky_exp(als[n * 8 + q] + adv);
        wsum = wself;
        acc16(wself, h1v[(size_t)n * 16 + 2 * q], h1v[(size_t)n * 16 + 2 * q + 1], acc);
        beg = rowstart[n];
        end = rowstart[n + 1];
    }
    int j = beg;
    int s0 = 0, s1 = 0, s2 = 0, s3 = 0;
    if (j + 4 <= end) {
        s0 = esrc[j]; s1 = esrc[j + 1]; s2 = esrc[j + 2]; s3 = esrc[j + 3];
    }
    for (; j + 4 <= end; ) {
        // issue gathers for current group
        float4 a0 = h1v[(size_t)s0 * 16 + 2 * q], b0 = h1v[(size_t)s0 * 16 + 2 * q + 1];
        float4 a1 = h1v[(size_t)s1 * 16 + 2 * q], b1v = h1v[(size_t)s1 * 16 + 2 * q + 1];
        float4 a2 = h1v[(size_t)s2 * 16 + 2 * q], b2 = h1v[(size_t)s2 * 16 + 2 * q + 1];
        float4 a3 = h1v[(size_t)s3 * 16 + 2 * q], b3 = h1v[(size_t)s3 * 16 + 2 * q + 1];
        float e0 = als[s0 * 8 + q], e1 = als[s1 * 8 + q];
        float e2 = als[s2 * 8 + q], e3 = als[s3 * 8 + q];
        // prefetch next group's indices while gathers are in flight
        int jn = j + 4;
        bool more = (jn + 4 <= end);
        int u0 = more ? esrc[jn]     : 0;
        int u1 = more ? esrc[jn + 1] : 0;
        int u2 = more ? esrc[jn + 2] : 0;
        int u3 = more ? esrc[jn + 3] : 0;
        float w0 = leaky_exp(e0 + adv), w1 = leaky_exp(e1 + adv);
        float w2 = leaky_exp(e2 + adv), w3 = leaky_exp(e3 + adv);
        wsum += (w0 + w1) + (w2 + w3);
        acc16(w0, a0, b0, acc);
        acc16(w1, a1, b1v, acc);
        acc16(w2, a2, b2, acc);
        acc16(w3, a3, b3, acc);
        s0 = u0; s1 = u1; s2 = u2; s3 = u3;
        j = jn;
    }
    for (; j < end; j++) {
        int s = esrc[j];
        float w = leaky_exp(als[s * 8 + q] + adv);
        wsum += w;
        acc16(w, h1v[(size_t)s * 16 + 2 * q], h1v[(size_t)s * 16 + 2 * q + 1], acc);
    }
    __align__(16) __half2 po[8];
    if (valid) {
        float inv = 1.f / (wsum + 1e-16f);
        const float* bf = b1 + q * 16;
#pragma unroll
        for (int k = 0; k < 8; k++) {
            float o0 = acc[2 * k] * inv + bf[2 * k];
            float o1 = acc[2 * k + 1] * inv + bf[2 * k + 1];
            o0 = (o0 > 0.f) ? o0 : (__expf(o0) - 1.f);  // ELU
            o1 = (o1 > 0.f) ? o1 : (__expf(o1) - 1.f);
            po[k] = __floats2half2_rn(o0, o1);
        }
    } else {
#pragma unroll
        for (int k = 0; k < 8; k++) po[k] = __floats2half2_rn(0.f, 0.f);
    }
    *(float4*)(actS + lrow * 136 + q * 16) = ((float4*)po)[0];
    *(float4*)(actS + lrow * 136 + q * 16 + 8) = ((float4*)po)[1];
    __syncthreads();
    int w4w = t >> 6;
    int m = lane & 15, quad = lane >> 4;
    int rt = w4w & 1;
    int ctbase = (w4w < 2) ? 0 : 1;
    f32x4 acc2[3];
#pragma unroll
    for (int f = 0; f < 3; f++) acc2[f] = (f32x4){0.f, 0.f, 0.f, 0.f};
    const _Float16* Arow2 = actS + (rt * 16 + m) * 136 + quad * 8;
    const _Float16* Brow2 = W2t + m * 128 + quad * 8;
#pragma unroll
    for (int kt = 0; kt < 4; kt++) {
        f16x8 a = *(const f16x8*)(Arow2 + kt * 32);
#pragma unroll
        for (int f = 0; f < 3; f++) {
            int ctf = ctbase + 2 * f;
            if (ctf < 5) {
                f16x8 bb = *(const f16x8*)(Brow2 + ctf * 2048 + kt * 32);
                acc2[f] = __builtin_amdgcn_mfma_f32_16x16x32_f16(a, bb, acc2[f], 0, 0, 0);
            }
        }
    }
    int secbase = (blockIdx.x & 7) * bdiv;
    int lnbase = (blockIdx.x >> 3) * 32 + rt * 16 + quad * 4;
#pragma unroll
    for (int r = 0; r < 4; r++) {
        int ln2 = lnbase + r;
        int n2 = secbase + ln2;
        if (ln2 < bdiv && n2 < N) {
#pragma unroll
            for (int f = 0; f < 3; f++) {
                int ctf = ctbase + 2 * f;
                if (ctf < 4) {
                    h2[(size_t)n2 * 64 + ctf * 16 + m] = __float2half(acc2[f][r]);
                } else if (ctf == 4) {
                    if (m == 0) al2s[n2] = acc2[f][r];
                    else if (m == 1) al2d[n2] = acc2[f][r];
                }
            }
        }
    }
}

// Aggregation layer 2. R26: esrc software prefetch.
__global__ __launch_bounds__(256) void agg2_kernel(const __half* __restrict__ h2,
                                                   const float* __restrict__ al2s,
                                                   const float* __restrict__ al2d,
                                                   const int* __restrict__ rowstart,
                                                   const int* __restrict__ esrc,
                                                   const float* __restrict__ b2,
                                                   float* __restrict__ out, int N) {
    int t = threadIdx.x;
    int lane = t & 63;
    int grp = lane >> 3;
    int q = lane & 7;
    int bdiv = (N + 7) >> 3;
    int ln = (blockIdx.x >> 3) * 32 + (t >> 6) * 8 + grp;
    if (ln >= bdiv) return;
    int n = (blockIdx.x & 7) * bdiv + ln;
    if (n >= N) return;
    const float4* h2v = (const float4*)h2;
    float adv = al2d[n];
    float acc[8];
#pragma unroll
    for (int k = 0; k < 8; k++) acc[k] = 0.f;
    float wsum = 0.f;
    {  // self loop
        float w = leaky_exp(al2s[n] + adv);
        wsum += w;
        acc8(w, h2v[(size_t)n * 8 + q], acc);
    }
    int beg = rowstart[n], end = rowstart[n + 1];
    int j = beg;
    int s0 = 0, s1 = 0, s2 = 0, s3 = 0;
    if (j + 4 <= end) {
        s0 = esrc[j]; s1 = esrc[j + 1]; s2 = esrc[j + 2]; s3 = esrc[j + 3];
    }
    for (; j + 4 <= end; ) {
        float4 a0 = h2v[(size_t)s0 * 8 + q];
        float4 a1 = h2v[(size_t)s1 * 8 + q];
        float4 a2 = h2v[(size_t)s2 * 8 + q];
        float4 a3 = h2v[(size_t)s3 * 8 + q];
        float e0 = al2s[s0], e1 = al2s[s1], e2 = al2s[s2], e3 = al2s[s3];
        int jn = j + 4;
        bool more = (jn + 4 <= end);
        int u0 = more ? esrc[jn]     : 0;
        int u1 = more ? esrc[jn + 1] : 0;
        int u2 = more ? esrc[jn + 2] : 0;
        int u3 = more ? esrc[jn + 3] : 0;
        float w0 = leaky_exp(e0 + adv), w1 = leaky_exp(e1 + adv);
        float w2 = leaky_exp(e2 + adv), w3 = leaky_exp(e3 + adv);
        wsum += (w0 + w1) + (w2 + w3);
        acc8(w0, a0, acc);
        acc8(w1, a1, acc);
        acc8(w2, a2, acc);
        acc8(w3, a3, acc);
        s0 = u0; s1 = u1; s2 = u2; s3 = u3;
        j = jn;
    }
    for (; j < end; j++) {
        int s = esrc[j];
        float w = leaky_exp(al2s[s] + adv);
        wsum += w;
        acc8(w, h2v[(size_t)s * 8 + q], acc);
    }
    float inv = 1.f / (wsum + 1e-16f);
    const float* bf = b2 + q * 8;
    float4* ov = (float4*)(out + (size_t)n * 64 + q * 8);
    ov[0] = make_float4(acc[0] * inv + bf[0], acc[1] * inv + bf[1],
                        acc[2] * inv + bf[2], acc[3] * inv + bf[3]);
    ov[1] = make_float4(acc[4] * inv + bf[4], acc[5] * inv + bf[5],
                        acc[6] * inv + bf[6], acc[7] * inv + bf[7]);
}

extern "C" void kernel_launch(void* const* d_in, const int* in_sizes, int n_in,
                              void* d_out, int out_size, void* d_ws, size_t ws_size,
                              hipStream_t stream) {
    (void)n_in; (void)out_size; (void)ws_size;
    const float* x   = (const float*)d_in[0];
    const int*   ei  = (const int*)d_in[1];
    const float* W1  = (const float*)d_in[2];
    const float* a1s = (const float*)d_in[3];
    const float* a1d = (const float*)d_in[4];
    const float* b1  = (const float*)d_in[5];
    const float* W2  = (const float*)d_in[6];
    const float* a2s = (const float*)d_in[7];
    const float* a2d = (const float*)d_in[8];
    const float* b2  = (const float*)d_in[9];
    float* out = (float*)d_out;

    const int N = in_sizes[0] / 128;
    const int E = in_sizes[1] / 2;
    const int* src = ei;
    const int* dst = ei + E;
    const int bdiv = (N + 7) / 8;

    char* wp = (char*)d_ws;
    auto alloc = [&](size_t bytes) -> void* {
        void* p = (void*)wp;
        wp += (bytes + 255) & ~(size_t)255;
        return p;
    };
    __half* h1   = (__half*)alloc((size_t)N * 128 * 2);
    __half* h2   = (__half*)alloc((size_t)N * 64 * 2 + 64 * 256);  // +pad
    float* al1s = (float*)alloc((size_t)N * 8 * 4);
    float* al1d = (float*)alloc((size_t)N * 8 * 4);
    float* al2s = (float*)alloc((size_t)N * 4);
    float* al2d = (float*)alloc((size_t)N * 4);
    int* bucketCnt = (int*)alloc(8 * 16 * 4);
    int* subcnt   = (int*)alloc((size_t)8 * NCHUNK * bdiv * 4);  // 6.4MB
    int* rowstart = (int*)alloc((size_t)(N + 1) * 4);
    int* esrc     = (int*)alloc((size_t)E * 4);
    unsigned* pairs = (unsigned*)alloc((size_t)8 * E * 4);  // packed 4B pairs
    int* blocksum = (int*)alloc(256 * 4);
    _Float16* W1t = (_Float16*)alloc(144 * 128 * 2);
    _Float16* W2t = (_Float16*)alloc(80 * 128 * 2);

    const int nbScan = (N + 255) / 256;
    const int gridH  = (E + 1023) / 1024;
    const int gridG1 = (N + 63) / 64;
    const int gridAggN = 8 * ((bdiv + 31) / 32);
    const int gridSort = 8 * NCHUNK;  // subhist & scatter

    // K0: augmented weights (block 0 also zeroes bucketCnt)
    augw_kernel<<<2, 256, 0, stream>>>(W1, a1s, a1d, W2, a2s, a2d, W1t, W2t,
                                       bucketCnt);
    // K1: gemm1 ∥ bucketing (no per-edge global atomics)
    gemm1_bucket_kernel<<<gridG1 + gridH, 256, 0, stream>>>(
        x, W1t, h1, al1s, al1d, N, gridG1, src, dst, E, bucketCnt, pairs);
    // K1b: per-chunk LDS histograms
    subhist_kernel<<<gridSort, 256, 0, stream>>>(bucketCnt, pairs, E, N, subcnt);
    scan1_kernel<<<nbScan, 256, 0, stream>>>(subcnt, N, rowstart, blocksum);
    scan23_kernel<<<(N + 256) / 256, 256, 0, stream>>>(rowstart, blocksum, nbScan,
                                                       subcnt, N, E);
    // K4: scatter via LDS cursors (no global atomics)
    scatter_kernel<<<gridSort, 256, 0, stream>>>(bucketCnt, pairs, E, N, subcnt, esrc);

    // agg1 with fused gemm2 epilogue
    agg1_gemm2_kernel<<<gridAggN, 256, 0, stream>>>(h1, al1s, al1d, rowstart, esrc,
                                                    b1, W2t, h2, al2s, al2d, N);
    agg2_kernel<<<gridAggN, 256, 0, stream>>>(h2, al2s, al2d, rowstart, esrc, b2, out, N);
}